// Round 17
// baseline (6688.544 us; speedup 1.0000x reference)
//
#include <hip/hip_runtime.h>
#include <hip/hip_bf16.h>
#include <stdint.h>

// Problem constants (fixed by the reference): T=512, B=64, IN=H=1024, L=2
#define TT 512
#define BB 64
#define HH 1024
#define BH 65536    // B*H elements
#define KD 2048     // IN+H == H+H

typedef __attribute__((ext_vector_type(8))) short short8;
typedef __attribute__((ext_vector_type(4))) float f32x4;

__device__ __forceinline__ unsigned short f2bf(float f) {
  union { float f; unsigned int u; } v; v.f = f;
  unsigned int r = v.u + 0x7fffu + ((v.u >> 16) & 1u);  // RNE
  return (unsigned short)(r >> 16);
}
__device__ __forceinline__ float fsig(float x)  { return 1.0f / (1.0f + __expf(-x)); }
__device__ __forceinline__ float ftanhf(float x){ return 1.0f - 2.0f / (__expf(2.0f * x) + 1.0f); }

// ---------------- x -> bf16 ----------------
__global__ void cvt_x_kernel(const float* __restrict__ x, unsigned short* __restrict__ xbf) {
  const int n4 = (TT * BB * 1024) / 4;
  int stride = gridDim.x * blockDim.x;
  for (int i = blockIdx.x * blockDim.x + threadIdx.x; i < n4; i += stride) {
    float4 v = ((const float4*)x)[i];
    unsigned long long p = (unsigned long long)f2bf(v.x)
        | ((unsigned long long)f2bf(v.y) << 16)
        | ((unsigned long long)f2bf(v.z) << 32)
        | ((unsigned long long)f2bf(v.w) << 48);
    ((unsigned long long*)xbf)[i] = p;
  }
}

// ---------------- W [4096][2048] f32 -> bf16, LDS-image layout (TRANSPOSED-C perm) ----
// Ws[g][kk 0..63][nrow 0..31][hi 0..3][8 bf16]  (16B chunks; 128 KB per slice g)
// nrow: nt=nrow>>4, rho=nrow&15 with GATE q=rho&3, COL jl=rho>>2
//   -> W row = q*1024 + g*8 + nt*4 + jl
// kk<32: k = kk*32 + hi*8 (x-half); kk>=32: k = 1024 + (kk-32)*32 + hi*8 (h-half)
__global__ void cvt_w_kernel(const float* __restrict__ W, unsigned short* __restrict__ Ws) {
  int idx = blockIdx.x * blockDim.x + threadIdx.x;   // < 128*64*32*4 = 1,048,576
  int hi = idx & 3;
  int nr = (idx >> 2) & 31;
  int kk = (idx >> 7) & 63;
  int g  = idx >> 13;
  int q  = nr & 3;            // gate (inner now)
  int jl = (nr >> 2) & 3;     // h-col within 4
  int nt = nr >> 4;
  int grow = (q << 10) + (g << 3) + (nt << 2) + jl;
  int k = ((kk < 32) ? (kk << 5) : (1024 + ((kk - 32) << 5))) + (hi << 3);
  const float* src = W + (size_t)grow * KD + k;
  float4 v0 = ((const float4*)src)[0];
  float4 v1 = ((const float4*)src)[1];
  unsigned long long p0 = (unsigned long long)f2bf(v0.x)
      | ((unsigned long long)f2bf(v0.y) << 16)
      | ((unsigned long long)f2bf(v0.z) << 32)
      | ((unsigned long long)f2bf(v0.w) << 48);
  unsigned long long p1 = (unsigned long long)f2bf(v1.x)
      | ((unsigned long long)f2bf(v1.y) << 16)
      | ((unsigned long long)f2bf(v1.z) << 32)
      | ((unsigned long long)f2bf(v1.w) << 48);
  unsigned long long* dst = (unsigned long long*)(Ws + ((size_t)g << 16) + (kk << 10) + (nr << 5) + (hi << 3));
  dst[0] = p0;
  dst[1] = p1;
}

// ---------------- initial h -> hist slot 0 ----------------
__global__ void init_state_kernel(const float* __restrict__ h0in,
                                  unsigned short* h0s0, unsigned short* h1s0) {
  int i = blockIdx.x * blockDim.x + threadIdx.x;  // < BH
  h0s0[i] = f2bf(h0in[i]);
  h1s0[i] = f2bf(h0in[BH + i]);
}

#define GLD(p)    __hip_atomic_load((p),  __ATOMIC_RELAXED, __HIP_MEMORY_SCOPE_AGENT)
#define GST(p, v) __hip_atomic_store((p), (v), __ATOMIC_RELAXED, __HIP_MEMORY_SCOPE_AGENT)
#define LLD(p)    __hip_atomic_load((p),  __ATOMIC_RELAXED, __HIP_MEMORY_SCOPE_WORKGROUP)
#define LADD(p)   __hip_atomic_fetch_add((p), 1, __ATOMIC_RELAXED, __HIP_MEMORY_SCOPE_WORKGROUP)

// spin until the 8 sub-counters (256B apart) sum to 128
__device__ __forceinline__ void poll128(int* base) {
  for (;;) {
    int s = 0;
#pragma unroll
    for (int j = 0; j < 8; j++)
      s += GLD(base + (j << 6));
    if (s >= 128) return;
    __builtin_amdgcn_s_sleep(1);
  }
}

// ---------------- persistent 2-layer LSTM, v12: decoupled A/B + 1-exposure loads ----------------
// 256 blocks x 512 threads, 1 block/CU. Blocks 0-127: layer0, 128-255: layer1.
// TRANSPOSED MFMA (v11): lane-local epilogue, zero cross-lane ops.
// Waves 0-3 (A): dependency-free GEMM one step ahead (L0: x[s+1]; L1: h0[s+2]
// gated lane0-poll cnt0[s+1]); ALL 32 frags loaded upfront (1 HBM exposure).
// Waves 4-7 (B): tight recurrence; ALL 32 h frags upfront (1 LLC exposure).
// NO per-step __syncthreads: A<->B handoff via LDS counters (intra-CU, ~60cy):
//   sealA[buf]: A-waves (lane0, after lgkmcnt(0)) +1 when pbuf[buf] written.
//       B at step s needs sealA[s&1] >= 4*((s+2)>>1).
//   consB[buf]: B-waves +1 right after reading pbuf into regs (A anti-dep:
//       A writing step s+1 needs consB[(s+1)&1] >= 4*((s+1)>>1)) -> A free-runs
//       <=1 step ahead; its HBM latency gets a full step of slack.
//   bdrain: B-waves +1 after per-wave s_waitcnt vmcnt(0) on sc1 h-stores;
//       wave 4 lane0 polls bdrain >= 4*(s+1) then publishes global cnt[L][s].
// A-straggle no longer blocks the publish chain.
__global__ __launch_bounds__(512, 2) void lstm_persist(
    const unsigned short* __restrict__ W0s, const unsigned short* __restrict__ W1s,
    const float* __restrict__ b0, const float* __restrict__ b1,
    const unsigned short* __restrict__ xbf,
    unsigned short* h0hist, unsigned short* h1hist,
    const float* __restrict__ c0in, float* out, int* cnt)
{
  __shared__ short8 wlds[8192];            // 128 KB: [kk 0..63][nrow 0..31][hi 0..3]
  __shared__ f32x4 pbuf[2][4][2][64];      // 16 KB partial double-buffer
  __shared__ int sealA[2];                 // pbuf sealed counts (cumulative, x4/wave)
  __shared__ int consB[2];                 // pbuf consumed counts
  __shared__ int bdrain;                   // B-wave drain count (cumulative)
  const int tid = threadIdx.x;
  const int bid = blockIdx.x;
  const int layer = bid >> 7;
  const int g = bid & 127;

  const unsigned short* Ws = layer ? W1s : W0s;
  const float* bias = layer ? b1 : b0;
  int* const cnt0 = cnt;                  // cnt0[s], stride 512 ints (8 sub-lines)
  int* const cnt1 = cnt + (TT << 9);      // cnt1[s], stride 512 ints

  if (tid == 0) { sealA[0] = 4; sealA[1] = 0; consB[0] = 0; consB[1] = 0; bdrain = 0; }

  // ---- stage weight slice once: linear 128KB copy ----
  {
    const short8* wsrc = (const short8*)(Ws + ((size_t)g << 16));
#pragma unroll
    for (int it = 0; it < 16; it++)
      wlds[tid + (it << 9)] = wsrc[tid + (it << 9)];
  }

  // ---- wave / lane mapping ----
  const int lane = tid & 63;
  const int w  = tid >> 6;        // 0..7
  const bool isA = (w < 4);
  const int mt = w & 3;           // m-tile (batch)
  const int m0 = mt << 4;
  const int n  = lane & 15;       // batch row within tile (C column now)
  const int hi = lane >> 4;       // k-subchunk for operands; h-col within 4 for C
  const short8* bbase0 = wlds + ((n << 2) + hi);          // n-tile 0 rows 0..15
  const short8* bbase1 = wlds + (((16 + n) << 2) + hi);   // n-tile 1 rows 16..31
  const int rowoff = ((m0 + n) << 10) + (hi << 3);        // x/h row base (elements)
  const int m = m0 + n;                                   // this lane's batch row (C)
  const int col0 = (g << 3) + hi;                         // h-col, n-tile 0
  const int col1 = col0 + 4;                              // h-col, n-tile 1

  unsigned short* const myhist = (layer == 0) ? h0hist : h1hist;
  int* const mycnt = (layer == 0) ? cnt0 : cnt1;

  // ---- B-wave state: 4 gate biases per n-tile + c registers ----
  float bq[2][4];
  float creg[2];
  if (!isA) {
#pragma unroll
    for (int nt2 = 0; nt2 < 2; nt2++) {
      int col = nt2 ? col1 : col0;
#pragma unroll
      for (int qg = 0; qg < 4; qg++)
        bq[nt2][qg] = bias[(qg << 10) + col];
      creg[nt2] = c0in[(size_t)layer * BH + (m << 10) + col];
    }
  }
  __syncthreads();   // weights staged + LDS counters initialized

  // ---- prologue: A-waves compute partial[0] (L1 gated lane0-poll cnt0[0]) ----
  if (isA) {
    if (layer == 1) {
      if (lane == 0) poll128(cnt0);
      asm volatile("" ::: "memory");
    }
    const unsigned short* asrc = ((layer == 0) ? xbf : h0hist + (size_t)BH) + rowoff;
    short8 xa[32];
#pragma unroll
    for (int j = 0; j < 32; j++) xa[j] = *(const short8*)(asrc + (j << 5));
    f32x4 a0 = {0.f, 0.f, 0.f, 0.f}, a1 = {0.f, 0.f, 0.f, 0.f};
#pragma unroll
    for (int kk = 0; kk < 32; kk++) {
      a0 = __builtin_amdgcn_mfma_f32_16x16x32_bf16(bbase0[kk << 7], xa[kk], a0, 0, 0, 0);
      a1 = __builtin_amdgcn_mfma_f32_16x16x32_bf16(bbase1[kk << 7], xa[kk], a1, 0, 0, 0);
    }
    pbuf[0][mt][0][lane] = a0;
    pbuf[0][mt][1][lane] = a1;
  }
  __syncthreads();   // partial[0] sealed (pre-seeded sealA[0]=4)

  for (int s = 0; s < TT; s++) {
    if (isA) {
      // ---- A-compute for step s+1 into pbuf[(s+1)&1] (free-running, <=1 ahead) ----
      if (s + 1 < TT) {
        const int buf = (s + 1) & 1;
        if (layer == 1) {
          if (lane == 0) poll128(cnt0 + ((s + 1) << 9));   // h0hist[s+2] ready
          asm volatile("" ::: "memory");
        }
        const int needC = 4 * ((s + 1) >> 1);              // anti-dep: B consumed prev use
        if (lane == 0 && needC) { while (LLD(&consB[buf]) < needC) {} }
        asm volatile("" ::: "memory");
        const unsigned short* asrc = ((layer == 0) ? xbf + (size_t)(s + 1) * BH
                                                   : h0hist + (size_t)(s + 2) * BH) + rowoff;
        short8 xa[32];
#pragma unroll
        for (int j = 0; j < 32; j++) xa[j] = *(const short8*)(asrc + (j << 5));
        f32x4 a0 = {0.f, 0.f, 0.f, 0.f}, a1 = {0.f, 0.f, 0.f, 0.f};
#pragma unroll
        for (int kk = 0; kk < 32; kk++) {
          a0 = __builtin_amdgcn_mfma_f32_16x16x32_bf16(bbase0[kk << 7], xa[kk], a0, 0, 0, 0);
          a1 = __builtin_amdgcn_mfma_f32_16x16x32_bf16(bbase1[kk << 7], xa[kk], a1, 0, 0, 0);
        }
        pbuf[buf][mt][0][lane] = a0;
        pbuf[buf][mt][1][lane] = a1;
        asm volatile("s_waitcnt lgkmcnt(0)" ::: "memory");  // pbuf visible
        if (lane == 0) LADD(&sealA[buf]);
      }
    } else {
      // ---- B: wait pbuf seal (LDS), grab partials, mark consumed ----
      const int needS = 4 * ((s + 2) >> 1);
      if (lane == 0) { while (LLD(&sealA[s & 1]) < needS) {} }
      asm volatile("" ::: "memory");
      f32x4 acc0 = pbuf[s & 1][mt][0][lane];
      f32x4 acc1 = pbuf[s & 1][mt][1][lane];
      asm volatile("s_waitcnt lgkmcnt(0)" ::: "memory");    // reads landed in regs
      if (lane == 0) LADD(&consB[s & 1]);
      // ---- tight wait: lane0 polls split counters directly ----
      if (s >= 1) {
        if (lane == 0) poll128(mycnt + ((s - 1) << 9));
        asm volatile("" ::: "memory");   // no load hoisting above the spin
      }
      // ---- single-exposure h fetch + recurrent GEMM ----
      const unsigned short* inB = myhist + (size_t)s * BH + rowoff;
      short8 ha[32];
#pragma unroll
      for (int j = 0; j < 32; j++) ha[j] = *(const short8*)(inB + (j << 5));
#pragma unroll
      for (int kk = 0; kk < 32; kk++) {
        acc0 = __builtin_amdgcn_mfma_f32_16x16x32_bf16(bbase0[(32 + kk) << 7], ha[kk], acc0, 0, 0, 0);
        acc1 = __builtin_amdgcn_mfma_f32_16x16x32_bf16(bbase1[(32 + kk) << 7], ha[kk], acc1, 0, 0, 0);
      }

      // ---- epilogue: LANE-LOCAL cell update, 2B sc1 h-stores ----
      float hsv[2];
      unsigned short* hb = myhist + (size_t)(s + 1) * BH;
#pragma unroll
      for (int nt2 = 0; nt2 < 2; nt2++) {
        f32x4 acc = nt2 ? acc1 : acc0;
        const int col = nt2 ? col1 : col0;
        float ig = fsig(acc[0] + bq[nt2][0]);
        float fg = fsig(acc[1] + bq[nt2][1]);
        float gg = ftanhf(acc[2] + bq[nt2][2]);
        float og = fsig(acc[3] + bq[nt2][3]);
        float cn = ig * gg + fg * creg[nt2];
        float hn = og * ftanhf(cn);
        creg[nt2] = cn;
        hsv[nt2] = hn;
        GST(hb + (m << 10) + col, f2bf(hn));
      }

      // ---- per-wave drain -> LDS count -> wave4 publishes global counter ----
      asm volatile("s_waitcnt vmcnt(0)" ::: "memory");
      if (lane == 0) LADD(&bdrain);
      if (w == 4 && lane == 0) {
        while (LLD(&bdrain) < 4 * (s + 1)) {}
        atomicAdd(mycnt + (s << 9) + ((g & 7) << 6), 1);
      }

      // ---- deferred f32 out-stores (off the critical path) ----
#pragma unroll
      for (int nt2 = 0; nt2 < 2; nt2++) {
        const int col = nt2 ? col1 : col0;
        const int idx = (m << 10) + col;
        float hn = hsv[nt2];
        if (layer == 1) {
          out[(size_t)s * BH + idx] = hn;                  // hlast[s]
          if (s == TT - 1) {
            out[(size_t)TT * BH + BH + idx] = hn;          // final h, layer 1
            out[(size_t)TT * BH + 3 * BH + idx] = creg[nt2];  // final c, layer 1
          }
        } else if (s == TT - 1) {
          out[(size_t)TT * BH + idx] = hn;                 // final h, layer 0
          out[(size_t)TT * BH + 2 * BH + idx] = creg[nt2]; // final c, layer 0
        }
      }
    }
  }
}

extern "C" void kernel_launch(void* const* d_in, const int* in_sizes, int n_in,
                              void* d_out, int out_size, void* d_ws, size_t ws_size,
                              hipStream_t stream) {
  (void)in_sizes; (void)n_in; (void)out_size; (void)ws_size;
  const float* x    = (const float*)d_in[0];
  const float* h0in = (const float*)d_in[1];
  const float* c0in = (const float*)d_in[2];
  const float* W0   = (const float*)d_in[3];
  const float* b0   = (const float*)d_in[4];
  const float* W1   = (const float*)d_in[5];
  const float* b1   = (const float*)d_in[6];
  float* out = (float*)d_out;

  char* ws = (char*)d_ws;
  const size_t HIST = (size_t)(TT + 1) * BH * sizeof(unsigned short);  // 67,239,936 B
  unsigned short* Xbf    = (unsigned short*)(ws);                      // 64 MB
  unsigned short* W0s    = (unsigned short*)(ws + 67108864);           // 16 MB
  unsigned short* W1s    = (unsigned short*)(ws + 83886080);           // 16 MB
  unsigned short* h0hist = (unsigned short*)(ws + 100663296);          // 64.1 MB
  unsigned short* h1hist = (unsigned short*)(ws + 100663296 + HIST);   // 64.1 MB
  int* cnt               = (int*)(ws + 100663296 + 2 * HIST);          // 2 MB counters

  const size_t CNT_BYTES = (size_t)2 * TT * 512 * sizeof(int);
  hipMemsetAsync(cnt, 0, CNT_BYTES, stream);
  cvt_x_kernel<<<2048, 256, 0, stream>>>(x, Xbf);
  cvt_w_kernel<<<4096, 256, 0, stream>>>(W0, W0s);
  cvt_w_kernel<<<4096, 256, 0, stream>>>(W1, W1s);
  init_state_kernel<<<256, 256, 0, stream>>>(h0in, h0hist, h1hist);

  lstm_persist<<<256, 512, 0, stream>>>(W0s, W1s, b0, b1, Xbf,
                                        h0hist, h1hist, c0in, out, cnt);
}

// Round 18
// 4203.379 us; speedup vs baseline: 1.5912x; 1.5912x over previous
//
#include <hip/hip_runtime.h>
#include <hip/hip_bf16.h>
#include <stdint.h>

// Problem constants (fixed by the reference): T=512, B=64, IN=H=1024, L=2
#define TT 512
#define BB 64
#define HH 1024
#define BH 65536    // B*H elements
#define KD 2048     // IN+H == H+H

typedef __attribute__((ext_vector_type(8))) short short8;
typedef __attribute__((ext_vector_type(4))) float f32x4;

__device__ __forceinline__ unsigned short f2bf(float f) {
  union { float f; unsigned int u; } v; v.f = f;
  unsigned int r = v.u + 0x7fffu + ((v.u >> 16) & 1u);  // RNE
  return (unsigned short)(r >> 16);
}
__device__ __forceinline__ float bf2f(unsigned short u) {
  union { unsigned int u; float f; } v; v.u = ((unsigned int)u) << 16; return v.f;
}
__device__ __forceinline__ float fsig(float x)  { return 1.0f / (1.0f + __expf(-x)); }
__device__ __forceinline__ float ftanhf(float x){ return 1.0f - 2.0f / (__expf(2.0f * x) + 1.0f); }

// ---------------- x -> bf16 (row-major, unchanged) ----------------
__global__ void cvt_x_kernel(const float* __restrict__ x, unsigned short* __restrict__ xbf) {
  const int n4 = (TT * BB * 1024) / 4;
  int stride = gridDim.x * blockDim.x;
  for (int i = blockIdx.x * blockDim.x + threadIdx.x; i < n4; i += stride) {
    float4 v = ((const float4*)x)[i];
    unsigned long long p = (unsigned long long)f2bf(v.x)
        | ((unsigned long long)f2bf(v.y) << 16)
        | ((unsigned long long)f2bf(v.z) << 32)
        | ((unsigned long long)f2bf(v.w) << 48);
    ((unsigned long long*)xbf)[i] = p;
  }
}

// ---------------- W [4096][2048] f32 -> bf16, LDS-image layout (TRANSPOSED-C perm) ----
// Ws[g][kk 0..63][nrow 0..31][hi 0..3][8 bf16]; nrow: nt=nrow>>4, q=nrow&3, jl=(nrow>>2)&3
//   -> W row = q*1024 + g*8 + nt*4 + jl ; kk<32: k=kk*32+hi*8 ; kk>=32: k=1024+(kk-32)*32+hi*8
__global__ void cvt_w_kernel(const float* __restrict__ W, unsigned short* __restrict__ Ws) {
  int idx = blockIdx.x * blockDim.x + threadIdx.x;   // < 1,048,576
  int hi = idx & 3;
  int nr = (idx >> 2) & 31;
  int kk = (idx >> 7) & 63;
  int g  = idx >> 13;
  int q  = nr & 3;
  int jl = (nr >> 2) & 3;
  int nt = nr >> 4;
  int grow = (q << 10) + (g << 3) + (nt << 2) + jl;
  int k = ((kk < 32) ? (kk << 5) : (1024 + ((kk - 32) << 5))) + (hi << 3);
  const float* src = W + (size_t)grow * KD + k;
  float4 v0 = ((const float4*)src)[0];
  float4 v1 = ((const float4*)src)[1];
  unsigned long long p0 = (unsigned long long)f2bf(v0.x)
      | ((unsigned long long)f2bf(v0.y) << 16)
      | ((unsigned long long)f2bf(v0.z) << 32)
      | ((unsigned long long)f2bf(v0.w) << 48);
  unsigned long long p1 = (unsigned long long)f2bf(v1.x)
      | ((unsigned long long)f2bf(v1.y) << 16)
      | ((unsigned long long)f2bf(v1.z) << 32)
      | ((unsigned long long)f2bf(v1.w) << 48);
  unsigned long long* dst = (unsigned long long*)(Ws + ((size_t)g << 16) + (kk << 10) + (nr << 5) + (hi << 3));
  dst[0] = p0;
  dst[1] = p1;
}

// ---------------- initial h -> hist slot 0 (BLOCKED layout [cb][m][8]) ----------------
__global__ void init_state_kernel(const float* __restrict__ h0in,
                                  unsigned short* h0s0, unsigned short* h1s0) {
  int i = blockIdx.x * blockDim.x + threadIdx.x;  // < BH
  int m = i >> 10, c = i & 1023;
  int dst = ((c >> 3) << 9) + (m << 3) + (c & 7);
  h0s0[dst] = f2bf(h0in[i]);
  h1s0[dst] = f2bf(h0in[BH + i]);
}

// ---------------- post-pass: blocked bf16 hist -> row-major fp32 out ----------------
// plane p<TT: out[p*BH+..] = h1hist[p+1]; p==TT: h0hist[TT] (final h L0);
// p==TT+1: h1hist[TT] (final h L1). Final c written by the persistent kernel.
__global__ void finalize_kernel(const unsigned short* __restrict__ h0hist,
                                const unsigned short* __restrict__ h1hist,
                                float* __restrict__ out) {
  const size_t NCH = (size_t)(TT + 2) * (BH / 8);
  size_t stride = (size_t)gridDim.x * blockDim.x;
  for (size_t i = (size_t)blockIdx.x * blockDim.x + threadIdx.x; i < NCH; i += stride) {
    int p  = (int)(i >> 13);     // BH/8 = 8192
    int ci = (int)(i & 8191);
    int cb = ci >> 6, m = ci & 63;
    const unsigned short* src;
    size_t dbase;
    if (p < TT)       { src = h1hist + (size_t)(p + 1) * BH; dbase = (size_t)p * BH; }
    else if (p == TT) { src = h0hist + (size_t)TT * BH;      dbase = (size_t)TT * BH; }
    else              { src = h1hist + (size_t)TT * BH;      dbase = (size_t)TT * BH + BH; }
    const unsigned short* sp = src + ((size_t)ci << 3);
    ushort4 v0 = ((const ushort4*)sp)[0];
    ushort4 v1 = ((const ushort4*)sp)[1];
    float* dp = out + dbase + (m << 10) + (cb << 3);
    *(float4*)(dp)     = make_float4(bf2f(v0.x), bf2f(v0.y), bf2f(v0.z), bf2f(v0.w));
    *(float4*)(dp + 4) = make_float4(bf2f(v1.x), bf2f(v1.y), bf2f(v1.z), bf2f(v1.w));
  }
}

#define GLD(p)    __hip_atomic_load((p),  __ATOMIC_RELAXED, __HIP_MEMORY_SCOPE_AGENT)
#define GST(p, v) __hip_atomic_store((p), (v), __ATOMIC_RELAXED, __HIP_MEMORY_SCOPE_AGENT)

// spin until the 8 sub-counters (256B apart) sum to 128
__device__ __forceinline__ void poll128(int* base) {
  for (;;) {
    int s = 0;
#pragma unroll
    for (int j = 0; j < 8; j++)
      s += GLD(base + (j << 6));
    if (s >= 128) return;
    __builtin_amdgcn_s_sleep(1);
  }
}

// ---------------- persistent 2-layer LSTM, v13: r16 + BLOCKED h (full-line stores) ----------------
// 256 blocks x 512 threads, 1 block/CU. Blocks 0-127: layer0, 128-255: layer1.
// TRANSPOSED MFMA (v11): lane-local epilogue. h hist slots use BLOCKED layout
// [cb=col>>3][m][col&7]: block g writes only cb==g -> each B-wave's 128 h values
// form one contiguous 256B run (full 128B lines; coalescer merges -> NO LLC
// write-allocate RMW on the drain). Reader fragments (8 k-contiguous cols) are
// one contiguous 16B dwordx4 at [cb=kk*4+hi][m][0..8). x stays row-major.
// NO out stores in the loop (hlast == h1hist slots 1..512; finalize_kernel
// expands blocked bf16 -> row-major fp32 at full BW). Only final-c stores once.
// Sync (r16): per-step __syncthreads (drains sc1 h-stores) -> tid0 atomicAdd
// 8-way-split cnt[L][s]; B-wave lane0 direct-polls; L1-A gated on cnt0[s+1].
__global__ __launch_bounds__(512, 2) void lstm_persist(
    const unsigned short* __restrict__ W0s, const unsigned short* __restrict__ W1s,
    const float* __restrict__ b0, const float* __restrict__ b1,
    const unsigned short* __restrict__ xbf,
    unsigned short* h0hist, unsigned short* h1hist,
    const float* __restrict__ c0in, float* out, int* cnt)
{
  __shared__ short8 wlds[8192];            // 128 KB: [kk 0..63][nrow 0..31][hi 0..3]
  __shared__ f32x4 pbuf[2][4][2][64];      // 16 KB partial double-buffer
  const int tid = threadIdx.x;
  const int bid = blockIdx.x;
  const int layer = bid >> 7;
  const int g = bid & 127;

  const unsigned short* Ws = layer ? W1s : W0s;
  const float* bias = layer ? b1 : b0;
  int* const cnt0 = cnt;                  // cnt0[s], stride 512 ints (8 sub-lines)
  int* const cnt1 = cnt + (TT << 9);      // cnt1[s], stride 512 ints

  // ---- stage weight slice once: linear 128KB copy ----
  {
    const short8* wsrc = (const short8*)(Ws + ((size_t)g << 16));
#pragma unroll
    for (int it = 0; it < 16; it++)
      wlds[tid + (it << 9)] = wsrc[tid + (it << 9)];
  }

  // ---- wave / lane mapping ----
  const int lane = tid & 63;
  const int w  = tid >> 6;        // 0..7
  const bool isA = (w < 4);
  const int mt = w & 3;           // m-tile (batch)
  const int m0 = mt << 4;
  const int n  = lane & 15;       // batch row within tile (C column)
  const int hi = lane >> 4;       // k-subchunk for operands; h-col within 4 for C
  const short8* bbase0 = wlds + ((n << 2) + hi);          // n-tile 0 rows 0..15
  const short8* bbase1 = wlds + (((16 + n) << 2) + hi);   // n-tile 1 rows 16..31
  const int m = m0 + n;                                   // this lane's batch row
  const int rowoff = (m << 10) + (hi << 3);               // x row base (row-major)
  const int bro = ((hi << 6) + m) << 3;                   // blocked h base: frag kk at bro + kk*2048
  const int col0 = (g << 3) + hi;                         // h-col, n-tile 0
  const int col1 = col0 + 4;                              // h-col, n-tile 1

  unsigned short* const myhist = (layer == 0) ? h0hist : h1hist;
  int* const mycnt = (layer == 0) ? cnt0 : cnt1;

  // ---- B-wave state: 4 gate biases per n-tile + c registers ----
  float bq[2][4];
  float creg[2];
  if (!isA) {
#pragma unroll
    for (int nt2 = 0; nt2 < 2; nt2++) {
      int col = nt2 ? col1 : col0;
#pragma unroll
      for (int qg = 0; qg < 4; qg++)
        bq[nt2][qg] = bias[(qg << 10) + col];
      creg[nt2] = c0in[(size_t)layer * BH + (m << 10) + col];
    }
  }
  __syncthreads();   // weights staged

  // ---- prologue: A-waves compute partial[0] (L1 gated lane0-poll cnt0[0]) ----
  if (isA) {
    if (layer == 1) {
      if (lane == 0) poll128(cnt0);
      asm volatile("" ::: "memory");
    }
    f32x4 a0 = {0.f, 0.f, 0.f, 0.f}, a1 = {0.f, 0.f, 0.f, 0.f};
    if (layer == 0) {
      const unsigned short* asrc = xbf + rowoff;
      short8 ha[8];
#pragma unroll
      for (int j = 0; j < 8; j++) ha[j] = *(const short8*)(asrc + (j << 5));
#pragma unroll
      for (int blk = 0; blk < 4; blk++)
#pragma unroll
        for (int j = 0; j < 8; j++) {
          int kk = (blk << 3) + j;
          a0 = __builtin_amdgcn_mfma_f32_16x16x32_bf16(bbase0[kk << 7], ha[j], a0, 0, 0, 0);
          a1 = __builtin_amdgcn_mfma_f32_16x16x32_bf16(bbase1[kk << 7], ha[j], a1, 0, 0, 0);
          if (blk < 3) ha[j] = *(const short8*)(asrc + ((kk + 8) << 5));
        }
    } else {
      const unsigned short* asrc = h0hist + (size_t)BH + bro;   // slot 1, blocked
      short8 ha[8];
#pragma unroll
      for (int j = 0; j < 8; j++) ha[j] = *(const short8*)(asrc + (j << 11));
#pragma unroll
      for (int blk = 0; blk < 4; blk++)
#pragma unroll
        for (int j = 0; j < 8; j++) {
          int kk = (blk << 3) + j;
          a0 = __builtin_amdgcn_mfma_f32_16x16x32_bf16(bbase0[kk << 7], ha[j], a0, 0, 0, 0);
          a1 = __builtin_amdgcn_mfma_f32_16x16x32_bf16(bbase1[kk << 7], ha[j], a1, 0, 0, 0);
          if (blk < 3) ha[j] = *(const short8*)(asrc + ((kk + 8) << 11));
        }
    }
    pbuf[0][mt][0][lane] = a0;
    pbuf[0][mt][1][lane] = a1;
  }
  __syncthreads();   // partial[0] sealed

  for (int s = 0; s < TT; s++) {
    if (isA) {
      // ---- A-compute for step s+1 into pbuf[(s+1)&1] ----
      if (s + 1 < TT) {
        f32x4 a0 = {0.f, 0.f, 0.f, 0.f}, a1 = {0.f, 0.f, 0.f, 0.f};
        if (layer == 0) {
          const unsigned short* asrc = xbf + (size_t)(s + 1) * BH + rowoff;
          short8 ha[8];
#pragma unroll
          for (int j = 0; j < 8; j++) ha[j] = *(const short8*)(asrc + (j << 5));
#pragma unroll
          for (int blk = 0; blk < 4; blk++)
#pragma unroll
            for (int j = 0; j < 8; j++) {
              int kk = (blk << 3) + j;
              a0 = __builtin_amdgcn_mfma_f32_16x16x32_bf16(bbase0[kk << 7], ha[j], a0, 0, 0, 0);
              a1 = __builtin_amdgcn_mfma_f32_16x16x32_bf16(bbase1[kk << 7], ha[j], a1, 0, 0, 0);
              if (blk < 3) ha[j] = *(const short8*)(asrc + ((kk + 8) << 5));
            }
        } else {
          if (lane == 0) poll128(cnt0 + ((s + 1) << 9));   // h0hist[s+2] ready
          asm volatile("" ::: "memory");
          const unsigned short* asrc = h0hist + (size_t)(s + 2) * BH + bro;  // blocked
          short8 ha[8];
#pragma unroll
          for (int j = 0; j < 8; j++) ha[j] = *(const short8*)(asrc + (j << 11));
#pragma unroll
          for (int blk = 0; blk < 4; blk++)
#pragma unroll
            for (int j = 0; j < 8; j++) {
              int kk = (blk << 3) + j;
              a0 = __builtin_amdgcn_mfma_f32_16x16x32_bf16(bbase0[kk << 7], ha[j], a0, 0, 0, 0);
              a1 = __builtin_amdgcn_mfma_f32_16x16x32_bf16(bbase1[kk << 7], ha[j], a1, 0, 0, 0);
              if (blk < 3) ha[j] = *(const short8*)(asrc + ((kk + 8) << 11));
            }
        }
        int buf = (s + 1) & 1;
        pbuf[buf][mt][0][lane] = a0;
        pbuf[buf][mt][1][lane] = a1;
      }
    } else {
      // ---- B tight wait: lane0 of THIS wave polls split counters directly ----
      if (s >= 1) {
        if (lane == 0) poll128(mycnt + ((s - 1) << 9));
        asm volatile("" ::: "memory");   // no load hoisting above the spin
      }
      // ---- recurrent GEMM: h[s] (blocked) x second K-half (8-deep rolling) ----
      f32x4 acc0 = pbuf[s & 1][mt][0][lane];
      f32x4 acc1 = pbuf[s & 1][mt][1][lane];
      const unsigned short* inB = myhist + (size_t)s * BH + bro;
      short8 ha[8];
#pragma unroll
      for (int j = 0; j < 8; j++) ha[j] = *(const short8*)(inB + (j << 11));
#pragma unroll
      for (int blk = 0; blk < 4; blk++)
#pragma unroll
        for (int j = 0; j < 8; j++) {
          int kk = (blk << 3) + j;
          acc0 = __builtin_amdgcn_mfma_f32_16x16x32_bf16(bbase0[(32 + kk) << 7], ha[j], acc0, 0, 0, 0);
          acc1 = __builtin_amdgcn_mfma_f32_16x16x32_bf16(bbase1[(32 + kk) << 7], ha[j], acc1, 0, 0, 0);
          if (blk < 3) ha[j] = *(const short8*)(inB + ((kk + 8) << 11));
        }

      // ---- epilogue: LANE-LOCAL cell update; blocked full-line sc1 h-stores ----
      unsigned short* hbb = myhist + (size_t)(s + 1) * BH + (((g << 6) + m) << 3);
#pragma unroll
      for (int nt2 = 0; nt2 < 2; nt2++) {
        f32x4 acc = nt2 ? acc1 : acc0;
        float ig = fsig(acc[0] + bq[nt2][0]);
        float fg = fsig(acc[1] + bq[nt2][1]);
        float gg = ftanhf(acc[2] + bq[nt2][2]);
        float og = fsig(acc[3] + bq[nt2][3]);
        float cn = ig * gg + fg * creg[nt2];
        float hn = og * ftanhf(cn);
        creg[nt2] = cn;
        GST(hbb + (nt2 << 2) + hi, f2bf(hn));
      }
    }

    // ---- end of step: seal pbuf[(s+1)&1], drain B h-stores, publish ----
    __syncthreads();
    if (tid == 0) atomicAdd(mycnt + (s << 9) + ((g & 7) << 6), 1);

    // ---- final c (once, off the per-step path) ----
    if (!isA && s == TT - 1) {
#pragma unroll
      for (int nt2 = 0; nt2 < 2; nt2++) {
        const int col = nt2 ? col1 : col0;
        out[(size_t)TT * BH + (size_t)(2 + layer) * BH + (m << 10) + col] = creg[nt2];
      }
    }
  }
}

extern "C" void kernel_launch(void* const* d_in, const int* in_sizes, int n_in,
                              void* d_out, int out_size, void* d_ws, size_t ws_size,
                              hipStream_t stream) {
  (void)in_sizes; (void)n_in; (void)out_size; (void)ws_size;
  const float* x    = (const float*)d_in[0];
  const float* h0in = (const float*)d_in[1];
  const float* c0in = (const float*)d_in[2];
  const float* W0   = (const float*)d_in[3];
  const float* b0   = (const float*)d_in[4];
  const float* W1   = (const float*)d_in[5];
  const float* b1   = (const float*)d_in[6];
  float* out = (float*)d_out;

  char* ws = (char*)d_ws;
  const size_t HIST = (size_t)(TT + 1) * BH * sizeof(unsigned short);  // 67,239,936 B
  unsigned short* Xbf    = (unsigned short*)(ws);                      // 64 MB
  unsigned short* W0s    = (unsigned short*)(ws + 67108864);           // 16 MB
  unsigned short* W1s    = (unsigned short*)(ws + 83886080);           // 16 MB
  unsigned short* h0hist = (unsigned short*)(ws + 100663296);          // 64.1 MB
  unsigned short* h1hist = (unsigned short*)(ws + 100663296 + HIST);   // 64.1 MB
  int* cnt               = (int*)(ws + 100663296 + 2 * HIST);          // 2 MB counters

  const size_t CNT_BYTES = (size_t)2 * TT * 512 * sizeof(int);
  hipMemsetAsync(cnt, 0, CNT_BYTES, stream);
  cvt_x_kernel<<<2048, 256, 0, stream>>>(x, Xbf);
  cvt_w_kernel<<<4096, 256, 0, stream>>>(W0, W0s);
  cvt_w_kernel<<<4096, 256, 0, stream>>>(W1, W1s);
  init_state_kernel<<<256, 256, 0, stream>>>(h0in, h0hist, h1hist);

  lstm_persist<<<256, 512, 0, stream>>>(W0s, W1s, b0, b1, Xbf,
                                        h0hist, h1hist, c0in, out, cnt);

  finalize_kernel<<<2048, 256, 0, stream>>>(h0hist, h1hist, out);
}